// Round 1
// baseline (713.975 us; speedup 1.0000x reference)
//
#include <hip/hip_runtime.h>
#include <hip/hip_bf16.h>

#define B_    2
#define S_    2048
#define DIM_  2048
#define H_    16
#define HKV_  4
#define D_    128
#define NQKV_ 3072
#define BS_   (B_*S_)

typedef __attribute__((ext_vector_type(8))) short short8;
typedef __attribute__((ext_vector_type(4))) float f32x4;

__device__ __forceinline__ unsigned short f2bf(float f) {
    union { float f; unsigned u; } v; v.f = f;
    unsigned r = (v.u + 0x7fffu + ((v.u >> 16) & 1u)) >> 16;
    return (unsigned short)r;
}
__device__ __forceinline__ float bf2f(unsigned short h) {
    union { unsigned u; float f; } v; v.u = ((unsigned)h) << 16;
    return v.f;
}

// ---------------- convert x (fp32 -> bf16), vectorized ----------------
__global__ void k_convert(const float* __restrict__ in, unsigned short* __restrict__ out, int n4) {
    int i = blockIdx.x * blockDim.x + threadIdx.x;
    if (i >= n4) return;
    float4 v = ((const float4*)in)[i];
    union { unsigned short us[4]; unsigned long long u; } o;
    o.us[0] = f2bf(v.x); o.us[1] = f2bf(v.y); o.us[2] = f2bf(v.z); o.us[3] = f2bf(v.w);
    ((unsigned long long*)out)[i] = o.u;
}

// ------------- transpose fp32 [K][N] -> bf16 [N][K] -------------------
__global__ void k_transpose(const float* __restrict__ W, unsigned short* __restrict__ WT,
                            int K, int N) {
    __shared__ float tile[64][65];
    const int k0 = blockIdx.x * 64, n0 = blockIdx.y * 64;
    const int tx = threadIdx.x & 63, ty = threadIdx.x >> 6;
    #pragma unroll
    for (int i = 0; i < 64; i += 4)
        tile[ty + i][tx] = W[(size_t)(k0 + ty + i) * N + n0 + tx];
    __syncthreads();
    #pragma unroll
    for (int i = 0; i < 64; i += 4)
        WT[(size_t)(n0 + ty + i) * K + k0 + tx] = f2bf(tile[tx][ty + i]);
}

// ------------- GEMM: C[M][N] = A[M][K] * BT[N][K]^T  (bf16 MFMA) ------
// 128x128 tile, BK=32, 4 waves (2x2), each wave 64x64 (4x4 frags of 16x16)
template<typename OUT_T>
__global__ __launch_bounds__(256, 2)
void k_gemm_bt(const unsigned short* __restrict__ A,
               const unsigned short* __restrict__ BT,
               OUT_T* __restrict__ C, int M, int N, int K)
{
    __shared__ unsigned short lds_a[128 * 32];
    __shared__ unsigned short lds_b[128 * 32];
    const int tid  = threadIdx.x;
    const int nbn  = N >> 7;
    const int bm   = blockIdx.x / nbn, bn = blockIdx.x % nbn;
    const int row0 = bm << 7, col0 = bn << 7;
    const int lane = tid & 63, wave = tid >> 6;
    const int wr = wave >> 1, wc = wave & 1;
    const int lg = lane >> 4, lr = lane & 15;

    f32x4 acc[4][4] = {};

    for (int kt = 0; kt < K; kt += 32) {
        __syncthreads();
        #pragma unroll
        for (int issue = 0; issue < 2; ++issue) {
            int e = issue * 2048 + wave * 512 + lane * 8;
            int r = e >> 5, kk = e & 31;
            const unsigned short* srcA = A  + (size_t)(row0 + r) * K + kt + kk;
            const unsigned short* srcB = BT + (size_t)(col0 + r) * K + kt + kk;
            unsigned short* dstA = lds_a + issue * 2048 + wave * 512;
            unsigned short* dstB = lds_b + issue * 2048 + wave * 512;
            __builtin_amdgcn_global_load_lds(
                (const __attribute__((address_space(1))) void*)srcA,
                (__attribute__((address_space(3))) void*)dstA, 16, 0, 0);
            __builtin_amdgcn_global_load_lds(
                (const __attribute__((address_space(1))) void*)srcB,
                (__attribute__((address_space(3))) void*)dstB, 16, 0, 0);
        }
        __syncthreads();
        short8 af[4], bf[4];
        #pragma unroll
        for (int m = 0; m < 4; ++m)
            af[m] = *(const short8*)&lds_a[(wr * 64 + m * 16 + lr) * 32 + lg * 8];
        #pragma unroll
        for (int n = 0; n < 4; ++n)
            bf[n] = *(const short8*)&lds_b[(wc * 64 + n * 16 + lr) * 32 + lg * 8];
        #pragma unroll
        for (int m = 0; m < 4; ++m)
            #pragma unroll
            for (int n = 0; n < 4; ++n)
                acc[m][n] = __builtin_amdgcn_mfma_f32_16x16x32_bf16(af[m], bf[n], acc[m][n], 0, 0, 0);
    }

    #pragma unroll
    for (int m = 0; m < 4; ++m)
        #pragma unroll
        for (int n = 0; n < 4; ++n)
            #pragma unroll
            for (int j = 0; j < 4; ++j) {
                int row = row0 + wr * 64 + m * 16 + lg * 4 + j;
                int col = col0 + wc * 64 + n * 16 + lr;
                if constexpr (sizeof(OUT_T) == 2)
                    C[(size_t)row * N + col] = (OUT_T)f2bf(acc[m][n][j]);
                else
                    C[(size_t)row * N + col] = (OUT_T)acc[m][n][j];
            }
}

// ------------------------- RoPE on Q and K (in-place) -----------------
__global__ void k_rope(unsigned short* __restrict__ qkv) {
    const int pair = blockIdx.x * 256 + threadIdx.x;   // 0..1279 (16 heads Q + 4 heads K, 64 pairs each)
    const int row  = blockIdx.y;                       // 0..BS_-1
    const int s    = row & (S_ - 1);
    const int col  = pair * 2;                         // cols 0..2559 cover Q then K
    const int t    = (col & 127) >> 1;                 // pair index within head
    const float theta = exp2f(-((float)(2 * t) / 128.0f) * 9.965784284662087f); // 1000^(-2t/128)
    const float ang = (float)s * theta;
    const float sn = sinf(ang), cs = cosf(ang);
    unsigned short* p = qkv + (size_t)row * NQKV_ + col;
    float x1 = bf2f(p[0]), x2 = bf2f(p[1]);
    p[0] = f2bf(x1 * cs - x2 * sn);
    p[1] = f2bf(x1 * sn + x2 * cs);
}

// --------- transpose V out of qkv: vt[(b*4+hk)][d][s] (bf16) ----------
__global__ void k_vtrans(const unsigned short* __restrict__ qkv, unsigned short* __restrict__ vt) {
    __shared__ unsigned short tile[64][65];
    const int s0 = blockIdx.x * 64;
    const int d0 = blockIdx.y * 64;
    const int bh = blockIdx.z;            // b*4+hk
    const int b = bh >> 2, hk = bh & 3;
    const int tx = threadIdx.x & 63, ty = threadIdx.x >> 6;
    #pragma unroll
    for (int i = 0; i < 64; i += 4)
        tile[i + ty][tx] = qkv[(size_t)(b * S_ + s0 + i + ty) * NQKV_ + (DIM_ + 512) + hk * D_ + d0 + tx];
    __syncthreads();
    #pragma unroll
    for (int i = 0; i < 64; i += 4)
        vt[((size_t)bh * D_ + d0 + i + ty) * S_ + s0 + tx] = tile[tx][i + ty];
}

// --------------------------- flash attention --------------------------
// grid (S/64, H, B); 4 waves/block; each wave owns 16 q rows, KV tiles of 32.
__global__ __launch_bounds__(256, 2)
void k_attn(const unsigned short* __restrict__ qkv,
            const unsigned short* __restrict__ vt,
            unsigned short* __restrict__ o)
{
    const int qt = blockIdx.x, h = blockIdx.y, b = blockIdx.z;
    const int tid = threadIdx.x;
    const int lane = tid & 63, wave = tid >> 6;
    const int lg = lane >> 4, lr = lane & 15;
    const int hk = h >> 2;
    const int q_base = qt * 64 + wave * 16;

    __shared__ unsigned short p_lds[4][16 * 32];

    // Q fragments (A-operand), held in registers for the whole KV loop
    short8 qf[4];
    {
        const unsigned short* qrow = qkv + (size_t)(b * S_ + q_base + lr) * NQKV_ + h * D_;
        #pragma unroll
        for (int dc = 0; dc < 4; ++dc)
            qf[dc] = *(const short8*)(qrow + dc * 32 + lg * 8);
    }

    float m_run[4], l_run[4];
    #pragma unroll
    for (int j = 0; j < 4; ++j) { m_run[j] = -1e30f; l_run[j] = 0.f; }
    f32x4 oacc[8] = {};

    const unsigned short* kbase = qkv + (size_t)(b * S_) * NQKV_ + DIM_ + hk * D_;
    const unsigned short* vtb   = vt + (size_t)(b * HKV_ + hk) * D_ * S_;
    const int ktmax = (q_base + 15) >> 5;
    const float scale = 0.08838834764831845f;   // 1/sqrt(128)

    for (int kt = 0; kt <= ktmax; ++kt) {
        const int k0 = kt * 32;
        f32x4 sc[2] = {};
        #pragma unroll
        for (int f = 0; f < 2; ++f)
            #pragma unroll
            for (int dc = 0; dc < 4; ++dc) {
                short8 kf = *(const short8*)(kbase + (size_t)(k0 + f * 16 + lr) * NQKV_ + dc * 32 + lg * 8);
                sc[f] = __builtin_amdgcn_mfma_f32_16x16x32_bf16(qf[dc], kf, sc[f], 0, 0, 0);
            }
        // scale + causal mask (score row = q_base+lg*4+j, col = k0+f*16+lr)
        #pragma unroll
        for (int f = 0; f < 2; ++f) {
            int kpos = k0 + f * 16 + lr;
            #pragma unroll
            for (int j = 0; j < 4; ++j) {
                int qpos = q_base + lg * 4 + j;
                float s = sc[f][j] * scale;
                sc[f][j] = (kpos <= qpos) ? s : -1e30f;
            }
        }
        // wave-parallel online softmax (16-lane groups hold a row)
        #pragma unroll
        for (int j = 0; j < 4; ++j) {
            float mx = fmaxf(sc[0][j], sc[1][j]);
            #pragma unroll
            for (int off = 1; off < 16; off <<= 1) mx = fmaxf(mx, __shfl_xor(mx, off));
            float mnew = fmaxf(m_run[j], mx);
            float corr = __expf(m_run[j] - mnew);
            float p0 = __expf(sc[0][j] - mnew);
            float p1 = __expf(sc[1][j] - mnew);
            float rs = p0 + p1;
            #pragma unroll
            for (int off = 1; off < 16; off <<= 1) rs += __shfl_xor(rs, off);
            l_run[j] = l_run[j] * corr + rs;
            m_run[j] = mnew;
            #pragma unroll
            for (int c = 0; c < 8; ++c) oacc[c][j] *= corr;
            p_lds[wave][(lg * 4 + j) * 32 + lr]      = f2bf(p0);
            p_lds[wave][(lg * 4 + j) * 32 + 16 + lr] = f2bf(p1);
        }
        // P (C-layout) -> LDS -> A-fragment layout; intra-wave only, no barrier
        asm volatile("s_waitcnt lgkmcnt(0)" ::: "memory");
        short8 pf = *(const short8*)&p_lds[wave][lr * 32 + lg * 8];
        #pragma unroll
        for (int c = 0; c < 8; ++c) {
            short8 vf = *(const short8*)(vtb + (size_t)(c * 16 + lr) * S_ + k0 + lg * 8);
            oacc[c] = __builtin_amdgcn_mfma_f32_16x16x32_bf16(pf, vf, oacc[c], 0, 0, 0);
        }
    }

    #pragma unroll
    for (int j = 0; j < 4; ++j) {
        float inv = 1.0f / l_run[j];
        #pragma unroll
        for (int c = 0; c < 8; ++c)
            o[(size_t)(b * S_ + q_base + lg * 4 + j) * DIM_ + h * D_ + c * 16 + lr] =
                f2bf(oacc[c][j] * inv);
    }
}

// ----------------------------------------------------------------------
extern "C" void kernel_launch(void* const* d_in, const int* in_sizes, int n_in,
                              void* d_out, int out_size, void* d_ws, size_t ws_size,
                              hipStream_t stream)
{
    const float* x  = (const float*)d_in[0];
    const float* Wq = (const float*)d_in[1];
    const float* Wk = (const float*)d_in[2];
    const float* Wv = (const float*)d_in[3];
    const float* Wo = (const float*)d_in[4];
    float* out = (float*)d_out;

    char* ws = (char*)d_ws;
    unsigned short* xb    = (unsigned short*)(ws);                       // 16,777,216 B
    unsigned short* wqkvt = (unsigned short*)(ws + 16777216);            // 12,582,912 B
    unsigned short* wot   = (unsigned short*)(ws + 29360128);            //  8,388,608 B
    unsigned short* qkv   = (unsigned short*)(ws + 37748736);            // 25,165,824 B
    unsigned short* vt    = (unsigned short*)(ws + 62914560);            //  4,194,304 B
    unsigned short* attno = (unsigned short*)(ws + 67108864);            // 16,777,216 B -> total 80 MB

    // 1. x -> bf16
    k_convert<<<(BS_ * DIM_ / 4) / 256, 256, 0, stream>>>(x, xb, BS_ * DIM_ / 4);

    // 2. weight transposes into bf16 B^T panels (QKV fused: rows 0..2047 Wq, 2048..2559 Wk, 2560..3071 Wv)
    k_transpose<<<dim3(DIM_ / 64, DIM_ / 64), 256, 0, stream>>>(Wq, wqkvt, DIM_, 2048);
    k_transpose<<<dim3(DIM_ / 64, 512 / 64), 256, 0, stream>>>(Wk, wqkvt + (size_t)2048 * 2048, DIM_, 512);
    k_transpose<<<dim3(DIM_ / 64, 512 / 64), 256, 0, stream>>>(Wv, wqkvt + (size_t)2560 * 2048, DIM_, 512);
    k_transpose<<<dim3(DIM_ / 64, DIM_ / 64), 256, 0, stream>>>(Wo, wot, 2048, 2048);

    // 3. QKV projection GEMM: qkv[4096][3072] = xb @ wqkvt^T
    k_gemm_bt<unsigned short><<<(BS_ / 128) * (NQKV_ / 128), 256, 0, stream>>>(
        xb, wqkvt, qkv, BS_, NQKV_, DIM_);

    // 4. RoPE in-place on Q and K columns
    k_rope<<<dim3(5, BS_), 256, 0, stream>>>(qkv);

    // 5. V -> vt[(b,hk)][d][s]
    k_vtrans<<<dim3(S_ / 64, D_ / 64, B_ * HKV_), 256, 0, stream>>>(qkv, vt);

    // 6. flash attention -> attno[4096][2048] bf16
    k_attn<<<dim3(S_ / 64, H_, B_), 256, 0, stream>>>(qkv, vt, attno);

    // 7. output GEMM: out[4096][2048] fp32 = attno @ wot^T
    k_gemm_bt<float><<<(BS_ / 128) * (DIM_ / 128), 256, 0, stream>>>(
        attno, wot, out, BS_, DIM_, DIM_);
}

// Round 6
// 406.046 us; speedup vs baseline: 1.7584x; 1.7584x over previous
//
#include <hip/hip_runtime.h>
#include <hip/hip_bf16.h>

#define B_    2
#define S_    2048
#define DIM_  2048
#define H_    16
#define HKV_  4
#define D_    128
#define NQKV_ 3072
#define BS_   (B_*S_)

typedef __attribute__((ext_vector_type(8))) short short8;
typedef __attribute__((ext_vector_type(4))) float f32x4;

__device__ __forceinline__ unsigned short f2bf(float f) {
    union { float f; unsigned u; } v; v.f = f;
    unsigned r = (v.u + 0x7fffu + ((v.u >> 16) & 1u)) >> 16;
    return (unsigned short)r;
}
__device__ __forceinline__ float bf2f(unsigned short h) {
    union { unsigned u; float f; } v; v.u = ((unsigned)h) << 16;
    return v.f;
}

// ---------------- convert x (fp32 -> bf16), vectorized ----------------
__global__ void k_convert(const float* __restrict__ in, unsigned short* __restrict__ out, int n4) {
    int i = blockIdx.x * blockDim.x + threadIdx.x;
    if (i >= n4) return;
    float4 v = ((const float4*)in)[i];
    union { unsigned short us[4]; unsigned long long u; } o;
    o.us[0] = f2bf(v.x); o.us[1] = f2bf(v.y); o.us[2] = f2bf(v.z); o.us[3] = f2bf(v.w);
    ((unsigned long long*)out)[i] = o.u;
}

// ------------- transpose fp32 [K][N] -> bf16 [N][K] -------------------
__global__ void k_transpose(const float* __restrict__ W, unsigned short* __restrict__ WT,
                            int K, int N) {
    __shared__ float tile[64][65];
    const int k0 = blockIdx.x * 64, n0 = blockIdx.y * 64;
    const int tx = threadIdx.x & 63, ty = threadIdx.x >> 6;
    #pragma unroll
    for (int i = 0; i < 64; i += 4)
        tile[ty + i][tx] = W[(size_t)(k0 + ty + i) * N + n0 + tx];
    __syncthreads();
    #pragma unroll
    for (int i = 0; i < 64; i += 4)
        WT[(size_t)(n0 + ty + i) * K + k0 + tx] = f2bf(tile[tx][ty + i]);
}

// ------------- GEMM: C[M][N] = A[M][K] * BT[N][K]^T  (bf16 MFMA) ------
// 128x128 tile, BK=32, 4 waves (2x2), each wave 64x64 (4x4 frags of 16x16)
// T1: XCD-aware bijective blockIdx swizzle (m204 form) for L2 locality.
template<typename OUT_T>
__global__ __launch_bounds__(256, 2)
void k_gemm_bt(const unsigned short* __restrict__ A,
               const unsigned short* __restrict__ BT,
               OUT_T* __restrict__ C, int M, int N, int K)
{
    __shared__ unsigned short lds_a[128 * 32];
    __shared__ unsigned short lds_b[128 * 32];
    const int tid  = threadIdx.x;
    const int nbn  = N >> 7;
    // --- XCD swizzle: orig round-robins across 8 XCDs; give each XCD a
    // contiguous chunk of tile space instead. Bijective for any nwg.
    const int nwg  = gridDim.x;
    const int orig = blockIdx.x;
    const int q8   = nwg >> 3, r8 = nwg & 7;
    const int xcd  = orig & 7, lid = orig >> 3;
    const int wgid = (xcd < r8 ? xcd * (q8 + 1) : r8 * (q8 + 1) + (xcd - r8) * q8) + lid;
    const int bm   = wgid / nbn, bn = wgid % nbn;
    const int row0 = bm << 7, col0 = bn << 7;
    const int lane = tid & 63, wave = tid >> 6;
    const int wr = wave >> 1, wc = wave & 1;
    const int lg = lane >> 4, lr = lane & 15;

    f32x4 acc[4][4] = {};

    for (int kt = 0; kt < K; kt += 32) {
        __syncthreads();
        #pragma unroll
        for (int issue = 0; issue < 2; ++issue) {
            int e = issue * 2048 + wave * 512 + lane * 8;
            int r = e >> 5, kk = e & 31;
            const unsigned short* srcA = A  + (size_t)(row0 + r) * K + kt + kk;
            const unsigned short* srcB = BT + (size_t)(col0 + r) * K + kt + kk;
            unsigned short* dstA = lds_a + issue * 2048 + wave * 512;
            unsigned short* dstB = lds_b + issue * 2048 + wave * 512;
            __builtin_amdgcn_global_load_lds(
                (const __attribute__((address_space(1))) void*)srcA,
                (__attribute__((address_space(3))) void*)dstA, 16, 0, 0);
            __builtin_amdgcn_global_load_lds(
                (const __attribute__((address_space(1))) void*)srcB,
                (__attribute__((address_space(3))) void*)dstB, 16, 0, 0);
        }
        __syncthreads();
        short8 af[4], bf[4];
        #pragma unroll
        for (int m = 0; m < 4; ++m)
            af[m] = *(const short8*)&lds_a[(wr * 64 + m * 16 + lr) * 32 + lg * 8];
        #pragma unroll
        for (int n = 0; n < 4; ++n)
            bf[n] = *(const short8*)&lds_b[(wc * 64 + n * 16 + lr) * 32 + lg * 8];
        #pragma unroll
        for (int m = 0; m < 4; ++m)
            #pragma unroll
            for (int n = 0; n < 4; ++n)
                acc[m][n] = __builtin_amdgcn_mfma_f32_16x16x32_bf16(af[m], bf[n], acc[m][n], 0, 0, 0);
    }

    #pragma unroll
    for (int m = 0; m < 4; ++m)
        #pragma unroll
        for (int n = 0; n < 4; ++n)
            #pragma unroll
            for (int j = 0; j < 4; ++j) {
                int row = row0 + wr * 64 + m * 16 + lg * 4 + j;
                int col = col0 + wc * 64 + n * 16 + lr;
                if constexpr (sizeof(OUT_T) == 2)
                    C[(size_t)row * N + col] = (OUT_T)f2bf(acc[m][n][j]);
                else
                    C[(size_t)row * N + col] = (OUT_T)acc[m][n][j];
            }
}

// ------------------------- RoPE on Q and K (in-place) -----------------
__global__ void k_rope(unsigned short* __restrict__ qkv) {
    const int pair = blockIdx.x * 256 + threadIdx.x;   // 0..1279 (16 heads Q + 4 heads K, 64 pairs each)
    const int row  = blockIdx.y;                       // 0..BS_-1
    const int s    = row & (S_ - 1);
    const int col  = pair * 2;                         // cols 0..2559 cover Q then K
    const int t    = (col & 127) >> 1;                 // pair index within head
    const float theta = exp2f(-((float)(2 * t) / 128.0f) * 9.965784284662087f); // 1000^(-2t/128)
    const float ang = (float)s * theta;
    const float sn = sinf(ang), cs = cosf(ang);
    unsigned short* p = qkv + (size_t)row * NQKV_ + col;
    float x1 = bf2f(p[0]), x2 = bf2f(p[1]);
    p[0] = f2bf(x1 * cs - x2 * sn);
    p[1] = f2bf(x1 * sn + x2 * cs);
}

// --------- transpose V out of qkv: vt[(b*4+hk)][d][s] (bf16) ----------
__global__ void k_vtrans(const unsigned short* __restrict__ qkv, unsigned short* __restrict__ vt) {
    __shared__ unsigned short tile[64][65];
    const int s0 = blockIdx.x * 64;
    const int d0 = blockIdx.y * 64;
    const int bh = blockIdx.z;            // b*4+hk
    const int b = bh >> 2, hk = bh & 3;
    const int tx = threadIdx.x & 63, ty = threadIdx.x >> 6;
    #pragma unroll
    for (int i = 0; i < 64; i += 4)
        tile[i + ty][tx] = qkv[(size_t)(b * S_ + s0 + i + ty) * NQKV_ + (DIM_ + 512) + hk * D_ + d0 + tx];
    __syncthreads();
    #pragma unroll
    for (int i = 0; i < 64; i += 4)
        vt[((size_t)bh * D_ + d0 + i + ty) * S_ + s0 + tx] = tile[tx][i + ty];
}

// --------------------------- flash attention --------------------------
// grid (S/128, H, B); 8 waves/block; wave w owns q rows [qb+16w, qb+16w+16).
// KV tiles of 64, K and V^T staged in padded LDS, shared by all 8 waves.
#define KPAD 136   // 128 + 8  (row stride in elements; 272 B == 4 banks mod 32)
#define VPAD 72    // 64 + 8   (144 B == 4 banks mod 32)
__global__ __launch_bounds__(512, 4)
void k_attn(const unsigned short* __restrict__ qkv,
            const unsigned short* __restrict__ vt,
            unsigned short* __restrict__ o)
{
    __shared__ unsigned short k_lds[64 * KPAD];    // 17408 B
    __shared__ unsigned short v_lds[128 * VPAD];   // 18432 B
    __shared__ unsigned short p_lds[8 * 16 * VPAD];// 18432 B

    const int qt = blockIdx.x, h = blockIdx.y, b = blockIdx.z;
    const int tid = threadIdx.x;
    const int lane = tid & 63, wave = tid >> 6;
    const int lg = lane >> 4, lr = lane & 15;
    const int hk = h >> 2;
    const int qb = qt * 128;
    const int q_base = qb + wave * 16;
    const int nt = qt * 2 + 2;                     // KV tiles this block iterates
    const int my_nt = ((q_base + 15) >> 6) + 1;    // tiles this wave actually needs

    // Q fragments (A-operand), registers for the whole KV loop
    short8 qf[4];
    {
        const unsigned short* qrow = qkv + (size_t)(b * S_ + q_base + lr) * NQKV_ + h * D_;
        #pragma unroll
        for (int dc = 0; dc < 4; ++dc)
            qf[dc] = *(const short8*)(qrow + dc * 32 + lg * 8);
    }

    float m_run[4], l_run[4];
    #pragma unroll
    for (int j = 0; j < 4; ++j) { m_run[j] = -1e30f; l_run[j] = 0.f; }
    f32x4 oacc[8] = {};

    const unsigned short* kglob = qkv + (size_t)(b * S_) * NQKV_ + DIM_ + hk * D_;
    const unsigned short* vglob = vt + (size_t)(b * HKV_ + hk) * D_ * S_;
    unsigned short* p_my = p_lds + wave * 16 * VPAD;
    const float scale = 0.08838834764831845f;      // 1/sqrt(128)

    for (int kt = 0; kt < nt; ++kt) {
        const int k0 = kt * 64;
        // ---- stage: issue global loads first (overlap other waves' tail) ----
        const int id1 = tid + 512;
        short8 ks0 = *(const short8*)(kglob + (size_t)(k0 + (tid >> 4)) * NQKV_ + (tid & 15) * 8);
        short8 ks1 = *(const short8*)(kglob + (size_t)(k0 + (id1 >> 4)) * NQKV_ + (id1 & 15) * 8);
        short8 vs0 = *(const short8*)(vglob + (size_t)(tid >> 3) * S_ + k0 + (tid & 7) * 8);
        short8 vs1 = *(const short8*)(vglob + (size_t)(id1 >> 3) * S_ + k0 + (id1 & 7) * 8);
        __syncthreads();   // previous tile's compute done reading LDS
        *(short8*)&k_lds[(tid >> 4) * KPAD + (tid & 15) * 8] = ks0;
        *(short8*)&k_lds[(id1 >> 4) * KPAD + (id1 & 15) * 8] = ks1;
        *(short8*)&v_lds[(tid >> 3) * VPAD + (tid & 7) * 8] = vs0;
        *(short8*)&v_lds[(id1 >> 3) * VPAD + (id1 & 7) * 8] = vs1;
        __syncthreads();   // staging visible to all waves

        if (kt >= my_nt) continue;

        // ---- QK^T: 16 q rows x 64 k cols ----
        f32x4 sc[4];
        #pragma unroll
        for (int f = 0; f < 4; ++f) sc[f] = (f32x4){0.f, 0.f, 0.f, 0.f};
        #pragma unroll
        for (int f = 0; f < 4; ++f)
            #pragma unroll
            for (int dc = 0; dc < 4; ++dc) {
                short8 kf = *(const short8*)&k_lds[(f * 16 + lr) * KPAD + dc * 32 + lg * 8];
                sc[f] = __builtin_amdgcn_mfma_f32_16x16x32_bf16(qf[dc], kf, sc[f], 0, 0, 0);
            }
        // scale + causal mask (score row = q_base+lg*4+j, col = k0+f*16+lr)
        #pragma unroll
        for (int f = 0; f < 4; ++f) {
            int kpos = k0 + f * 16 + lr;
            #pragma unroll
            for (int j = 0; j < 4; ++j) {
                int qpos = q_base + lg * 4 + j;
                float s = sc[f][j] * scale;
                sc[f][j] = (kpos <= qpos) ? s : -1e30f;
            }
        }
        // ---- online softmax (16-lane groups hold a row) ----
        #pragma unroll
        for (int j = 0; j < 4; ++j) {
            float mx = fmaxf(fmaxf(sc[0][j], sc[1][j]), fmaxf(sc[2][j], sc[3][j]));
            #pragma unroll
            for (int off = 1; off < 16; off <<= 1) mx = fmaxf(mx, __shfl_xor(mx, off));
            float mnew = fmaxf(m_run[j], mx);
            float corr = __expf(m_run[j] - mnew);
            float p0 = __expf(sc[0][j] - mnew);
            float p1 = __expf(sc[1][j] - mnew);
            float p2 = __expf(sc[2][j] - mnew);
            float p3 = __expf(sc[3][j] - mnew);
            float rs = (p0 + p1) + (p2 + p3);
            #pragma unroll
            for (int off = 1; off < 16; off <<= 1) rs += __shfl_xor(rs, off);
            l_run[j] = l_run[j] * corr + rs;
            m_run[j] = mnew;
            #pragma unroll
            for (int c = 0; c < 8; ++c) oacc[c][j] *= corr;
            int prow = (lg * 4 + j) * VPAD;
            p_my[prow + lr]      = f2bf(p0);
            p_my[prow + 16 + lr] = f2bf(p1);
            p_my[prow + 32 + lr] = f2bf(p2);
            p_my[prow + 48 + lr] = f2bf(p3);
        }
        // ---- P (C-layout) -> LDS -> A-fragment; intra-wave, no barrier ----
        asm volatile("s_waitcnt lgkmcnt(0)" ::: "memory");
        #pragma unroll
        for (int kh = 0; kh < 2; ++kh) {
            short8 pf = *(const short8*)&p_my[lr * VPAD + kh * 32 + lg * 8];
            #pragma unroll
            for (int c = 0; c < 8; ++c) {
                short8 vf = *(const short8*)&v_lds[(c * 16 + lr) * VPAD + kh * 32 + lg * 8];
                oacc[c] = __builtin_amdgcn_mfma_f32_16x16x32_bf16(pf, vf, oacc[c], 0, 0, 0);
            }
        }
    }

    #pragma unroll
    for (int j = 0; j < 4; ++j) {
        float inv = 1.0f / l_run[j];
        #pragma unroll
        for (int c = 0; c < 8; ++c)
            o[(size_t)(b * S_ + q_base + lg * 4 + j) * DIM_ + h * D_ + c * 16 + lr] =
                f2bf(oacc[c][j] * inv);
    }
}

// ----------------------------------------------------------------------
extern "C" void kernel_launch(void* const* d_in, const int* in_sizes, int n_in,
                              void* d_out, int out_size, void* d_ws, size_t ws_size,
                              hipStream_t stream)
{
    const float* x  = (const float*)d_in[0];
    const float* Wq = (const float*)d_in[1];
    const float* Wk = (const float*)d_in[2];
    const float* Wv = (const float*)d_in[3];
    const float* Wo = (const float*)d_in[4];
    float* out = (float*)d_out;

    char* ws = (char*)d_ws;
    unsigned short* xb    = (unsigned short*)(ws);                       // 16,777,216 B
    unsigned short* wqkvt = (unsigned short*)(ws + 16777216);            // 12,582,912 B
    unsigned short* wot   = (unsigned short*)(ws + 29360128);            //  8,388,608 B
    unsigned short* qkv   = (unsigned short*)(ws + 37748736);            // 25,165,824 B
    unsigned short* vt    = (unsigned short*)(ws + 62914560);            //  4,194,304 B
    unsigned short* attno = (unsigned short*)(ws + 67108864);            // 16,777,216 B -> total 80 MB

    // 1. x -> bf16
    k_convert<<<(BS_ * DIM_ / 4) / 256, 256, 0, stream>>>(x, xb, BS_ * DIM_ / 4);

    // 2. weight transposes into bf16 B^T panels (QKV fused: rows 0..2047 Wq, 2048..2559 Wk, 2560..3071 Wv)
    k_transpose<<<dim3(DIM_ / 64, DIM_ / 64), 256, 0, stream>>>(Wq, wqkvt, DIM_, 2048);
    k_transpose<<<dim3(DIM_ / 64, 512 / 64), 256, 0, stream>>>(Wk, wqkvt + (size_t)2048 * 2048, DIM_, 512);
    k_transpose<<<dim3(DIM_ / 64, 512 / 64), 256, 0, stream>>>(Wv, wqkvt + (size_t)2560 * 2048, DIM_, 512);
    k_transpose<<<dim3(DIM_ / 64, DIM_ / 64), 256, 0, stream>>>(Wo, wot, 2048, 2048);

    // 3. QKV projection GEMM: qkv[4096][3072] = xb @ wqkvt^T
    k_gemm_bt<unsigned short><<<(BS_ / 128) * (NQKV_ / 128), 256, 0, stream>>>(
        xb, wqkvt, qkv, BS_, NQKV_, DIM_);

    // 4. RoPE in-place on Q and K columns
    k_rope<<<dim3(5, BS_), 256, 0, stream>>>(qkv);

    // 5. V -> vt[(b,hk)][d][s]
    k_vtrans<<<dim3(S_ / 64, D_ / 64, B_ * HKV_), 256, 0, stream>>>(qkv, vt);

    // 6. flash attention -> attno[4096][2048] bf16
    k_attn<<<dim3(S_ / 128, H_, B_), 512, 0, stream>>>(qkv, vt, attno);

    // 7. output GEMM: out[4096][2048] fp32 = attno @ wot^T
    k_gemm_bt<float><<<(BS_ / 128) * (DIM_ / 128), 256, 0, stream>>>(
        attno, wot, out, BS_, DIM_, DIM_);
}

// Round 8
// 375.822 us; speedup vs baseline: 1.8998x; 1.0804x over previous
//
#include <hip/hip_runtime.h>
#include <hip/hip_bf16.h>

#define B_    2
#define S_    2048
#define DIM_  2048
#define H_    16
#define HKV_  4
#define D_    128
#define NQKV_ 3072
#define BS_   (B_*S_)

typedef __attribute__((ext_vector_type(8))) short short8;
typedef __attribute__((ext_vector_type(4))) float f32x4;

__device__ __forceinline__ unsigned short f2bf(float f) {
    union { float f; unsigned u; } v; v.f = f;
    unsigned r = (v.u + 0x7fffu + ((v.u >> 16) & 1u)) >> 16;
    return (unsigned short)r;
}
__device__ __forceinline__ float bf2f(unsigned short h) {
    union { unsigned u; float f; } v; v.u = ((unsigned)h) << 16;
    return v.f;
}

// ---------------- convert x (fp32 -> bf16), vectorized ----------------
__global__ void k_convert(const float* __restrict__ in, unsigned short* __restrict__ out, int n4) {
    int i = blockIdx.x * blockDim.x + threadIdx.x;
    if (i >= n4) return;
    float4 v = ((const float4*)in)[i];
    union { unsigned short us[4]; unsigned long long u; } o;
    o.us[0] = f2bf(v.x); o.us[1] = f2bf(v.y); o.us[2] = f2bf(v.z); o.us[3] = f2bf(v.w);
    ((unsigned long long*)out)[i] = o.u;
}

// ------------- transpose fp32 [K][N] -> bf16 [N][K] -------------------
__global__ void k_transpose(const float* __restrict__ W, unsigned short* __restrict__ WT,
                            int K, int N) {
    __shared__ float tile[64][65];
    const int k0 = blockIdx.x * 64, n0 = blockIdx.y * 64;
    const int tx = threadIdx.x & 63, ty = threadIdx.x >> 6;
    #pragma unroll
    for (int i = 0; i < 64; i += 4)
        tile[ty + i][tx] = W[(size_t)(k0 + ty + i) * N + n0 + tx];
    __syncthreads();
    #pragma unroll
    for (int i = 0; i < 64; i += 4)
        WT[(size_t)(n0 + ty + i) * K + k0 + tx] = f2bf(tile[tx][ty + i]);
}

// ------------- GEMM: C[M][N] = A[M][K] * BT[N][K]^T  (bf16 MFMA) ------
// 128x128 tile, BK=64 (m97-family config), 4 waves (2x2), 64x64/wave.
// T1: XCD-aware bijective blockIdx swizzle for L2 locality.
template<typename OUT_T>
__global__ __launch_bounds__(256, 2)
void k_gemm_bt(const unsigned short* __restrict__ A,
               const unsigned short* __restrict__ BT,
               OUT_T* __restrict__ C, int M, int N, int K)
{
    __shared__ unsigned short lds_a[128 * 64];
    __shared__ unsigned short lds_b[128 * 64];
    const int tid  = threadIdx.x;
    const int nbn  = N >> 7;
    const int nwg  = gridDim.x;
    const int orig = blockIdx.x;
    const int q8   = nwg >> 3, r8 = nwg & 7;
    const int xcd  = orig & 7, lid = orig >> 3;
    const int wgid = (xcd < r8 ? xcd * (q8 + 1) : r8 * (q8 + 1) + (xcd - r8) * q8) + lid;
    const int bm   = wgid / nbn, bn = wgid % nbn;
    const int row0 = bm << 7, col0 = bn << 7;
    const int lane = tid & 63, wave = tid >> 6;
    const int wr = wave >> 1, wc = wave & 1;
    const int lg = lane >> 4, lr = lane & 15;

    f32x4 acc[4][4] = {};

    for (int kt = 0; kt < K; kt += 64) {
        __syncthreads();
        #pragma unroll
        for (int issue = 0; issue < 4; ++issue) {
            int e = issue * 2048 + wave * 512 + lane * 8;   // element in [128][64] tile
            int r = e >> 6, kk = e & 63;
            const unsigned short* srcA = A  + (size_t)(row0 + r) * K + kt + kk;
            const unsigned short* srcB = BT + (size_t)(col0 + r) * K + kt + kk;
            unsigned short* dstA = lds_a + issue * 2048 + wave * 512;  // +lane*8 by HW
            unsigned short* dstB = lds_b + issue * 2048 + wave * 512;
            __builtin_amdgcn_global_load_lds(
                (const __attribute__((address_space(1))) void*)srcA,
                (__attribute__((address_space(3))) void*)dstA, 16, 0, 0);
            __builtin_amdgcn_global_load_lds(
                (const __attribute__((address_space(1))) void*)srcB,
                (__attribute__((address_space(3))) void*)dstB, 16, 0, 0);
        }
        __syncthreads();
        #pragma unroll
        for (int kc = 0; kc < 2; ++kc) {
            short8 af[4], bf[4];
            #pragma unroll
            for (int m = 0; m < 4; ++m)
                af[m] = *(const short8*)&lds_a[(wr * 64 + m * 16 + lr) * 64 + kc * 32 + lg * 8];
            #pragma unroll
            for (int n = 0; n < 4; ++n)
                bf[n] = *(const short8*)&lds_b[(wc * 64 + n * 16 + lr) * 64 + kc * 32 + lg * 8];
            #pragma unroll
            for (int m = 0; m < 4; ++m)
                #pragma unroll
                for (int n = 0; n < 4; ++n)
                    acc[m][n] = __builtin_amdgcn_mfma_f32_16x16x32_bf16(af[m], bf[n], acc[m][n], 0, 0, 0);
        }
    }

    #pragma unroll
    for (int m = 0; m < 4; ++m)
        #pragma unroll
        for (int n = 0; n < 4; ++n)
            #pragma unroll
            for (int j = 0; j < 4; ++j) {
                int row = row0 + wr * 64 + m * 16 + lg * 4 + j;
                int col = col0 + wc * 64 + n * 16 + lr;
                if constexpr (sizeof(OUT_T) == 2)
                    C[(size_t)row * N + col] = (OUT_T)f2bf(acc[m][n][j]);
                else
                    C[(size_t)row * N + col] = (OUT_T)acc[m][n][j];
            }
}

// ------------------------- RoPE on Q and K (in-place) -----------------
__global__ void k_rope(unsigned short* __restrict__ qkv) {
    const int pair = blockIdx.x * 256 + threadIdx.x;
    const int row  = blockIdx.y;
    const int s    = row & (S_ - 1);
    const int col  = pair * 2;
    const int t    = (col & 127) >> 1;
    const float theta = exp2f(-((float)(2 * t) / 128.0f) * 9.965784284662087f);
    const float ang = (float)s * theta;
    const float sn = sinf(ang), cs = cosf(ang);
    unsigned short* p = qkv + (size_t)row * NQKV_ + col;
    float x1 = bf2f(p[0]), x2 = bf2f(p[1]);
    p[0] = f2bf(x1 * cs - x2 * sn);
    p[1] = f2bf(x1 * sn + x2 * cs);
}

// --------- transpose V out of qkv: vt[(b*4+hk)][d][s] (bf16) ----------
__global__ void k_vtrans(const unsigned short* __restrict__ qkv, unsigned short* __restrict__ vt) {
    __shared__ unsigned short tile[64][65];
    const int s0 = blockIdx.x * 64;
    const int d0 = blockIdx.y * 64;
    const int bh = blockIdx.z;
    const int b = bh >> 2, hk = bh & 3;
    const int tx = threadIdx.x & 63, ty = threadIdx.x >> 6;
    #pragma unroll
    for (int i = 0; i < 64; i += 4)
        tile[i + ty][tx] = qkv[(size_t)(b * S_ + s0 + i + ty) * NQKV_ + (DIM_ + 512) + hk * D_ + d0 + tx];
    __syncthreads();
    #pragma unroll
    for (int i = 0; i < 64; i += 4)
        vt[((size_t)bh * D_ + d0 + i + ty) * S_ + s0 + tx] = tile[tx][i + ty];
}

// --------------------------- flash attention --------------------------
// grid (8, H, B); 8 waves/block. Block handles q-tile PAIR (qlo, 15-qlo)
// sequentially -> uniform 34 KV tiles/block (causal load balance).
// Next tile's K/V global loads issued before compute (latency hidden).
#define KPAD 136   // 128 + 8
#define VPAD 72    // 64 + 8
#define SCALE2 0.12751739f   // (1/sqrt(128)) * log2(e); softmax in base-2 domain

#define STAGE_LOAD(K0) do {                                                            \
    ks0 = *(const short8*)(kglob + (size_t)((K0) + (tid >> 4)) * NQKV_ + (tid & 15) * 8);      \
    ks1 = *(const short8*)(kglob + (size_t)((K0) + 32 + (tid >> 4)) * NQKV_ + (tid & 15) * 8); \
    vs0 = *(const short8*)(vglob + (size_t)(tid >> 3) * S_ + (K0) + (tid & 7) * 8);            \
    vs1 = *(const short8*)(vglob + (size_t)(64 + (tid >> 3)) * S_ + (K0) + (tid & 7) * 8);     \
} while (0)

// One KV tile: write staged regs->LDS, prefetch next, compute if active.
#define ATTN_TILE(QF, QBASE, MYNT, TL, K0, HASNEXT, K0NEXT) do {                       \
    __syncthreads();                                                                   \
    *(short8*)&k_lds[(tid >> 4) * KPAD + (tid & 15) * 8] = ks0;                        \
    *(short8*)&k_lds[(32 + (tid >> 4)) * KPAD + (tid & 15) * 8] = ks1;                 \
    *(short8*)&v_lds[(tid >> 3) * VPAD + (tid & 7) * 8] = vs0;                         \
    *(short8*)&v_lds[(64 + (tid >> 3)) * VPAD + (tid & 7) * 8] = vs1;                  \
    __syncthreads();                                                                   \
    if (HASNEXT) { STAGE_LOAD(K0NEXT); }                                               \
    if ((TL) < (MYNT)) {                                                               \
        f32x4 sc[4];                                                                   \
        _Pragma("unroll")                                                              \
        for (int f = 0; f < 4; ++f) sc[f] = (f32x4){0.f, 0.f, 0.f, 0.f};               \
        _Pragma("unroll")                                                              \
        for (int f = 0; f < 4; ++f)                                                    \
            _Pragma("unroll")                                                          \
            for (int dc = 0; dc < 4; ++dc) {                                           \
                short8 kf = *(const short8*)&k_lds[(f * 16 + lr) * KPAD + dc * 32 + lg * 8]; \
                sc[f] = __builtin_amdgcn_mfma_f32_16x16x32_bf16(QF[dc], kf, sc[f], 0, 0, 0); \
            }                                                                          \
        _Pragma("unroll")                                                              \
        for (int f = 0; f < 4; ++f) {                                                  \
            int kpos = (K0) + f * 16 + lr;                                             \
            _Pragma("unroll")                                                          \
            for (int j = 0; j < 4; ++j) {                                              \
                int qpos = (QBASE) + lg * 4 + j;                                       \
                float s = sc[f][j] * SCALE2;                                           \
                sc[f][j] = (kpos <= qpos) ? s : -1e30f;                                \
            }                                                                          \
        }                                                                              \
        _Pragma("unroll")                                                              \
        for (int j = 0; j < 4; ++j) {                                                  \
            float mx = fmaxf(fmaxf(sc[0][j], sc[1][j]), fmaxf(sc[2][j], sc[3][j]));    \
            _Pragma("unroll")                                                          \
            for (int off = 1; off < 16; off <<= 1) mx = fmaxf(mx, __shfl_xor(mx, off));\
            float mnew = fmaxf(m_run[j], mx);                                          \
            float corr = exp2f(m_run[j] - mnew);                                       \
            float p0 = exp2f(sc[0][j] - mnew);                                         \
            float p1 = exp2f(sc[1][j] - mnew);                                         \
            float p2 = exp2f(sc[2][j] - mnew);                                         \
            float p3 = exp2f(sc[3][j] - mnew);                                         \
            float rs = (p0 + p1) + (p2 + p3);                                          \
            _Pragma("unroll")                                                          \
            for (int off = 1; off < 16; off <<= 1) rs += __shfl_xor(rs, off);          \
            l_run[j] = l_run[j] * corr + rs;                                           \
            m_run[j] = mnew;                                                           \
            _Pragma("unroll")                                                          \
            for (int c = 0; c < 8; ++c) oacc[c][j] *= corr;                            \
            int prow = (lg * 4 + j) * VPAD;                                            \
            p_my[prow + lr]      = f2bf(p0);                                           \
            p_my[prow + 16 + lr] = f2bf(p1);                                           \
            p_my[prow + 32 + lr] = f2bf(p2);                                           \
            p_my[prow + 48 + lr] = f2bf(p3);                                           \
        }                                                                              \
        asm volatile("s_waitcnt lgkmcnt(0)" ::: "memory");                             \
        _Pragma("unroll")                                                              \
        for (int kh = 0; kh < 2; ++kh) {                                               \
            short8 pf = *(const short8*)&p_my[lr * VPAD + kh * 32 + lg * 8];           \
            _Pragma("unroll")                                                          \
            for (int c = 0; c < 8; ++c) {                                              \
                short8 vf = *(const short8*)&v_lds[(c * 16 + lr) * VPAD + kh * 32 + lg * 8]; \
                oacc[c] = __builtin_amdgcn_mfma_f32_16x16x32_bf16(pf, vf, oacc[c], 0, 0, 0); \
            }                                                                          \
        }                                                                              \
    }                                                                                  \
} while (0)

__global__ __launch_bounds__(512, 2)
void k_attn(const unsigned short* __restrict__ qkv,
            const unsigned short* __restrict__ vt,
            unsigned short* __restrict__ o)
{
    __shared__ unsigned short k_lds[64 * KPAD];
    __shared__ unsigned short v_lds[128 * VPAD];
    __shared__ unsigned short p_lds[8 * 16 * VPAD];

    const int h = blockIdx.y, b = blockIdx.z;
    const int tid = threadIdx.x;
    const int lane = tid & 63, wave = tid >> 6;
    const int lg = lane >> 4, lr = lane & 15;
    const int hk = h >> 2;
    const int qlo = blockIdx.x, qhi = 15 - qlo;     // paired q-tiles, uniform work
    const int ntA = 2 * qlo + 2, ntB = 2 * qhi + 2; // ntA + ntB == 34
    const int qbaseA = qlo * 128 + wave * 16;
    const int qbaseB = qhi * 128 + wave * 16;
    const int myA = ((qbaseA + 15) >> 6) + 1;
    const int myB = ((qbaseB + 15) >> 6) + 1;

    // Q fragments for both phases, registers for the whole kernel
    short8 qfA[4], qfB[4];
    {
        const unsigned short* qrA = qkv + (size_t)(b * S_ + qbaseA + lr) * NQKV_ + h * D_;
        const unsigned short* qrB = qkv + (size_t)(b * S_ + qbaseB + lr) * NQKV_ + h * D_;
        #pragma unroll
        for (int dc = 0; dc < 4; ++dc) {
            qfA[dc] = *(const short8*)(qrA + dc * 32 + lg * 8);
            qfB[dc] = *(const short8*)(qrB + dc * 32 + lg * 8);
        }
    }

    float m_run[4], l_run[4];
    #pragma unroll
    for (int j = 0; j < 4; ++j) { m_run[j] = -1e30f; l_run[j] = 0.f; }
    f32x4 oacc[8] = {};

    const unsigned short* kglob = qkv + (size_t)(b * S_) * NQKV_ + DIM_ + hk * D_;
    const unsigned short* vglob = vt + (size_t)(b * HKV_ + hk) * D_ * S_;
    unsigned short* p_my = p_lds + wave * 16 * VPAD;

    auto writeO = [&](int qb2) {
        #pragma unroll
        for (int j = 0; j < 4; ++j) {
            float inv = 1.0f / l_run[j];
            #pragma unroll
            for (int c = 0; c < 8; ++c)
                o[(size_t)(b * S_ + qb2 + lg * 4 + j) * DIM_ + h * D_ + c * 16 + lr] =
                    f2bf(oacc[c][j] * inv);
        }
    };

    short8 ks0, ks1, vs0, vs1;
    STAGE_LOAD(0);                                   // prologue: tile 0 of phase A

    // ---- phase A: q-tile qlo ----
    for (int t = 0; t < ntA; ++t) {
        int k0 = t * 64;
        int k0n = (t + 1 < ntA) ? (t + 1) * 64 : 0;  // next tile (phase B restarts at 0)
        ATTN_TILE(qfA, qbaseA, myA, t, k0, 1, k0n);
    }
    writeO(qbaseA);
    #pragma unroll
    for (int j = 0; j < 4; ++j) { m_run[j] = -1e30f; l_run[j] = 0.f; }
    #pragma unroll
    for (int c = 0; c < 8; ++c) oacc[c] = (f32x4){0.f, 0.f, 0.f, 0.f};

    // ---- phase B: q-tile qhi ----
    for (int t = 0; t < ntB; ++t) {
        int k0 = t * 64;
        int k0n = (t + 1) * 64;
        ATTN_TILE(qfB, qbaseB, myB, t, k0, (t + 1 < ntB), k0n);
    }
    writeO(qbaseB);
}

// ----------------------------------------------------------------------
extern "C" void kernel_launch(void* const* d_in, const int* in_sizes, int n_in,
                              void* d_out, int out_size, void* d_ws, size_t ws_size,
                              hipStream_t stream)
{
    const float* x  = (const float*)d_in[0];
    const float* Wq = (const float*)d_in[1];
    const float* Wk = (const float*)d_in[2];
    const float* Wv = (const float*)d_in[3];
    const float* Wo = (const float*)d_in[4];
    float* out = (float*)d_out;

    char* ws = (char*)d_ws;
    unsigned short* xb    = (unsigned short*)(ws);
    unsigned short* wqkvt = (unsigned short*)(ws + 16777216);
    unsigned short* wot   = (unsigned short*)(ws + 29360128);
    unsigned short* qkv   = (unsigned short*)(ws + 37748736);
    unsigned short* vt    = (unsigned short*)(ws + 62914560);
    unsigned short* attno = (unsigned short*)(ws + 67108864);

    // 1. x -> bf16
    k_convert<<<(BS_ * DIM_ / 4) / 256, 256, 0, stream>>>(x, xb, BS_ * DIM_ / 4);

    // 2. weight transposes into bf16 B^T panels
    k_transpose<<<dim3(DIM_ / 64, DIM_ / 64), 256, 0, stream>>>(Wq, wqkvt, DIM_, 2048);
    k_transpose<<<dim3(DIM_ / 64, 512 / 64), 256, 0, stream>>>(Wk, wqkvt + (size_t)2048 * 2048, DIM_, 512);
    k_transpose<<<dim3(DIM_ / 64, 512 / 64), 256, 0, stream>>>(Wv, wqkvt + (size_t)2560 * 2048, DIM_, 512);
    k_transpose<<<dim3(DIM_ / 64, DIM_ / 64), 256, 0, stream>>>(Wo, wot, 2048, 2048);

    // 3. QKV projection GEMM
    k_gemm_bt<unsigned short><<<(BS_ / 128) * (NQKV_ / 128), 256, 0, stream>>>(
        xb, wqkvt, qkv, BS_, NQKV_, DIM_);

    // 4. RoPE in-place on Q and K
    k_rope<<<dim3(5, BS_), 256, 0, stream>>>(qkv);

    // 5. V -> vt[(b,hk)][d][s]
    k_vtrans<<<dim3(S_ / 64, D_ / 64, B_ * HKV_), 256, 0, stream>>>(qkv, vt);

    // 6. flash attention (paired q-tiles)
    k_attn<<<dim3(8, H_, B_), 512, 0, stream>>>(qkv, vt, attno);

    // 7. output GEMM
    k_gemm_bt<float><<<(BS_ / 128) * (DIM_ / 128), 256, 0, stream>>>(
        attno, wot, out, BS_, DIM_, DIM_);
}

// Round 9
// 349.102 us; speedup vs baseline: 2.0452x; 1.0765x over previous
//
#include <hip/hip_runtime.h>
#include <hip/hip_bf16.h>

#define B_    2
#define S_    2048
#define DIM_  2048
#define H_    16
#define HKV_  4
#define D_    128
#define NQKV_ 3072
#define BS_   (B_*S_)

typedef __attribute__((ext_vector_type(8))) short short8;
typedef __attribute__((ext_vector_type(4))) float f32x4;

__device__ __forceinline__ unsigned short f2bf(float f) {
    union { float f; unsigned u; } v; v.f = f;
    unsigned r = (v.u + 0x7fffu + ((v.u >> 16) & 1u)) >> 16;
    return (unsigned short)r;
}
__device__ __forceinline__ float bf2f(unsigned short h) {
    union { unsigned u; float f; } v; v.u = ((unsigned)h) << 16;
    return v.f;
}

// ---------------- convert x (fp32 -> bf16), vectorized ----------------
__global__ void k_convert(const float* __restrict__ in, unsigned short* __restrict__ out, int n4) {
    int i = blockIdx.x * blockDim.x + threadIdx.x;
    if (i >= n4) return;
    float4 v = ((const float4*)in)[i];
    union { unsigned short us[4]; unsigned long long u; } o;
    o.us[0] = f2bf(v.x); o.us[1] = f2bf(v.y); o.us[2] = f2bf(v.z); o.us[3] = f2bf(v.w);
    ((unsigned long long*)out)[i] = o.u;
}

// ------------- transpose fp32 [K][N] -> bf16 [N][K] -------------------
__global__ void k_transpose(const float* __restrict__ W, unsigned short* __restrict__ WT,
                            int K, int N) {
    __shared__ float tile[64][65];
    const int k0 = blockIdx.x * 64, n0 = blockIdx.y * 64;
    const int tx = threadIdx.x & 63, ty = threadIdx.x >> 6;
    #pragma unroll
    for (int i = 0; i < 64; i += 4)
        tile[ty + i][tx] = W[(size_t)(k0 + ty + i) * N + n0 + tx];
    __syncthreads();
    #pragma unroll
    for (int i = 0; i < 64; i += 4)
        WT[(size_t)(n0 + ty + i) * K + k0 + tx] = f2bf(tile[tx][ty + i]);
}

// ------------- GEMM: C[M][N] = A[M][K] * BT[N][K]^T  (bf16 MFMA) ------
// 128x128 tile, BK=64, 4 waves (2x2), 64x64/wave. XCD bijective swizzle.
template<typename OUT_T>
__global__ __launch_bounds__(256, 2)
void k_gemm_bt(const unsigned short* __restrict__ A,
               const unsigned short* __restrict__ BT,
               OUT_T* __restrict__ C, int M, int N, int K)
{
    __shared__ unsigned short lds_a[128 * 64];
    __shared__ unsigned short lds_b[128 * 64];
    const int tid  = threadIdx.x;
    const int nbn  = N >> 7;
    const int nwg  = gridDim.x;
    const int orig = blockIdx.x;
    const int q8   = nwg >> 3, r8 = nwg & 7;
    const int xcd  = orig & 7, lid = orig >> 3;
    const int wgid = (xcd < r8 ? xcd * (q8 + 1) : r8 * (q8 + 1) + (xcd - r8) * q8) + lid;
    const int bm   = wgid / nbn, bn = wgid % nbn;
    const int row0 = bm << 7, col0 = bn << 7;
    const int lane = tid & 63, wave = tid >> 6;
    const int wr = wave >> 1, wc = wave & 1;
    const int lg = lane >> 4, lr = lane & 15;

    f32x4 acc[4][4] = {};

    for (int kt = 0; kt < K; kt += 64) {
        __syncthreads();
        #pragma unroll
        for (int issue = 0; issue < 4; ++issue) {
            int e = issue * 2048 + wave * 512 + lane * 8;
            int r = e >> 6, kk = e & 63;
            const unsigned short* srcA = A  + (size_t)(row0 + r) * K + kt + kk;
            const unsigned short* srcB = BT + (size_t)(col0 + r) * K + kt + kk;
            unsigned short* dstA = lds_a + issue * 2048 + wave * 512;
            unsigned short* dstB = lds_b + issue * 2048 + wave * 512;
            __builtin_amdgcn_global_load_lds(
                (const __attribute__((address_space(1))) void*)srcA,
                (__attribute__((address_space(3))) void*)dstA, 16, 0, 0);
            __builtin_amdgcn_global_load_lds(
                (const __attribute__((address_space(1))) void*)srcB,
                (__attribute__((address_space(3))) void*)dstB, 16, 0, 0);
        }
        __syncthreads();
        #pragma unroll
        for (int kc = 0; kc < 2; ++kc) {
            short8 af[4], bf[4];
            #pragma unroll
            for (int m = 0; m < 4; ++m)
                af[m] = *(const short8*)&lds_a[(wr * 64 + m * 16 + lr) * 64 + kc * 32 + lg * 8];
            #pragma unroll
            for (int n = 0; n < 4; ++n)
                bf[n] = *(const short8*)&lds_b[(wc * 64 + n * 16 + lr) * 64 + kc * 32 + lg * 8];
            #pragma unroll
            for (int m = 0; m < 4; ++m)
                #pragma unroll
                for (int n = 0; n < 4; ++n)
                    acc[m][n] = __builtin_amdgcn_mfma_f32_16x16x32_bf16(af[m], bf[n], acc[m][n], 0, 0, 0);
        }
    }

    #pragma unroll
    for (int m = 0; m < 4; ++m)
        #pragma unroll
        for (int n = 0; n < 4; ++n)
            #pragma unroll
            for (int j = 0; j < 4; ++j) {
                int row = row0 + wr * 64 + m * 16 + lg * 4 + j;
                int col = col0 + wc * 64 + n * 16 + lr;
                if constexpr (sizeof(OUT_T) == 2)
                    C[(size_t)row * N + col] = (OUT_T)f2bf(acc[m][n][j]);
                else
                    C[(size_t)row * N + col] = (OUT_T)acc[m][n][j];
            }
}

// ------------------------- RoPE on Q and K (in-place) -----------------
__global__ void k_rope(unsigned short* __restrict__ qkv) {
    const int pair = blockIdx.x * 256 + threadIdx.x;
    const int row  = blockIdx.y;
    const int s    = row & (S_ - 1);
    const int col  = pair * 2;
    const int t    = (col & 127) >> 1;
    const float theta = exp2f(-((float)(2 * t) / 128.0f) * 9.965784284662087f);
    const float ang = (float)s * theta;
    const float sn = sinf(ang), cs = cosf(ang);
    unsigned short* p = qkv + (size_t)row * NQKV_ + col;
    float x1 = bf2f(p[0]), x2 = bf2f(p[1]);
    p[0] = f2bf(x1 * cs - x2 * sn);
    p[1] = f2bf(x1 * sn + x2 * cs);
}

// --------- transpose V out of qkv: vt[(b*4+hk)][d][s] (bf16) ----------
__global__ void k_vtrans(const unsigned short* __restrict__ qkv, unsigned short* __restrict__ vt) {
    __shared__ unsigned short tile[64][65];
    const int s0 = blockIdx.x * 64;
    const int d0 = blockIdx.y * 64;
    const int bh = blockIdx.z;
    const int b = bh >> 2, hk = bh & 3;
    const int tx = threadIdx.x & 63, ty = threadIdx.x >> 6;
    #pragma unroll
    for (int i = 0; i < 64; i += 4)
        tile[i + ty][tx] = qkv[(size_t)(b * S_ + s0 + i + ty) * NQKV_ + (DIM_ + 512) + hk * D_ + d0 + tx];
    __syncthreads();
    #pragma unroll
    for (int i = 0; i < 64; i += 4)
        vt[((size_t)bh * D_ + d0 + i + ty) * S_ + s0 + tx] = tile[tx][i + ty];
}

// --------------------------- flash attention --------------------------
// grid (8, H, B); 8 waves/block; paired q-tiles (qlo, 15-qlo) = 34 KV tiles.
// SWAPPED QK^T: sc = mfma(K,Q) -> lane owns one q-row (q=lr), k=f*16+lg*4+j.
// Softmax fully in-register (scalar m/l per lane, 4 shuffles/tile).
// P redistributed to B-operand layout via 16 shfl + selects (no P LDS).
#define KPAD 136   // 128 + 8
#define VPAD 72    // 64 + 8
#define SCALE2 0.12751739f   // (1/sqrt(128)) * log2(e)

#define STAGE_LOAD(K0) do {                                                            \
    ks0 = *(const short8*)(kglob + (size_t)((K0) + (tid >> 4)) * NQKV_ + (tid & 15) * 8);      \
    ks1 = *(const short8*)(kglob + (size_t)((K0) + 32 + (tid >> 4)) * NQKV_ + (tid & 15) * 8); \
    vs0 = *(const short8*)(vglob + (size_t)(tid >> 3) * S_ + (K0) + (tid & 7) * 8);            \
    vs1 = *(const short8*)(vglob + (size_t)(64 + (tid >> 3)) * S_ + (K0) + (tid & 7) * 8);     \
} while (0)

#define ATTN_TILE(QF, QBASE, MYNT, TL, K0, HASNEXT, K0NEXT) do {                       \
    __syncthreads();                                                                   \
    *(short8*)&k_lds[(tid >> 4) * KPAD + (tid & 15) * 8] = ks0;                        \
    *(short8*)&k_lds[(32 + (tid >> 4)) * KPAD + (tid & 15) * 8] = ks1;                 \
    *(short8*)&v_lds[(tid >> 3) * VPAD + (tid & 7) * 8] = vs0;                         \
    *(short8*)&v_lds[(64 + (tid >> 3)) * VPAD + (tid & 7) * 8] = vs1;                  \
    __syncthreads();                                                                   \
    if (HASNEXT) { STAGE_LOAD(K0NEXT); }                                               \
    if ((TL) < (MYNT)) {                                                               \
        f32x4 sc[4];                                                                   \
        _Pragma("unroll")                                                              \
        for (int f = 0; f < 4; ++f) sc[f] = (f32x4){0.f, 0.f, 0.f, 0.f};               \
        _Pragma("unroll")                                                              \
        for (int f = 0; f < 4; ++f)                                                    \
            _Pragma("unroll")                                                          \
            for (int dc = 0; dc < 4; ++dc) {                                           \
                short8 kf = *(const short8*)&k_lds[(f * 16 + lr) * KPAD + dc * 32 + lg * 8]; \
                sc[f] = __builtin_amdgcn_mfma_f32_16x16x32_bf16(kf, QF[dc], sc[f], 0, 0, 0); \
            }                                                                          \
        const int qpos = (QBASE) + lr;                                                 \
        float mxl = -1e30f;                                                            \
        _Pragma("unroll")                                                              \
        for (int f = 0; f < 4; ++f)                                                    \
            _Pragma("unroll")                                                          \
            for (int j = 0; j < 4; ++j) {                                              \
                int kpos = (K0) + f * 16 + lg * 4 + j;                                 \
                float s = sc[f][j] * SCALE2;                                           \
                sc[f][j] = (kpos <= qpos) ? s : -1e30f;                                \
                mxl = fmaxf(mxl, sc[f][j]);                                            \
            }                                                                          \
        mxl = fmaxf(mxl, __shfl_xor(mxl, 16));                                         \
        mxl = fmaxf(mxl, __shfl_xor(mxl, 32));                                         \
        float mnew = fmaxf(m_run, mxl);                                                \
        float corr = exp2f(m_run - mnew);                                              \
        m_run = mnew;                                                                  \
        float rs = 0.f;                                                                \
        _Pragma("unroll")                                                              \
        for (int f = 0; f < 4; ++f)                                                    \
            _Pragma("unroll")                                                          \
            for (int j = 0; j < 4; ++j) {                                              \
                sc[f][j] = exp2f(sc[f][j] - mnew);                                     \
                rs += sc[f][j];                                                        \
            }                                                                          \
        rs += __shfl_xor(rs, 16);                                                      \
        rs += __shfl_xor(rs, 32);                                                      \
        l_run = l_run * corr + rs;                                                     \
        _Pragma("unroll")                                                              \
        for (int c = 0; c < 8; ++c)                                                    \
            _Pragma("unroll")                                                          \
            for (int j = 0; j < 4; ++j) oacc[c][j] *= corr;                            \
        unsigned pk[4][2];                                                             \
        _Pragma("unroll")                                                              \
        for (int f = 0; f < 4; ++f) {                                                  \
            pk[f][0] = (unsigned)f2bf(sc[f][0]) | ((unsigned)f2bf(sc[f][1]) << 16);    \
            pk[f][1] = (unsigned)f2bf(sc[f][2]) | ((unsigned)f2bf(sc[f][3]) << 16);    \
        }                                                                              \
        const int srcA = (lg & 1) * 32 + lr;                                           \
        const int srcB = srcA + 16;                                                    \
        const bool hiF = ((lg >> 1) != 0);                                             \
        _Pragma("unroll")                                                              \
        for (int kh = 0; kh < 2; ++kh) {                                               \
            unsigned a0 = __shfl(pk[2 * kh][0], srcA), b0 = __shfl(pk[2 * kh + 1][0], srcA); \
            unsigned a1 = __shfl(pk[2 * kh][1], srcA), b1 = __shfl(pk[2 * kh + 1][1], srcA); \
            unsigned a2 = __shfl(pk[2 * kh][0], srcB), b2 = __shfl(pk[2 * kh + 1][0], srcB); \
            unsigned a3 = __shfl(pk[2 * kh][1], srcB), b3 = __shfl(pk[2 * kh + 1][1], srcB); \
            union { unsigned u[4]; short8 s8; } pf_;                                   \
            pf_.u[0] = hiF ? b0 : a0; pf_.u[1] = hiF ? b1 : a1;                        \
            pf_.u[2] = hiF ? b2 : a2; pf_.u[3] = hiF ? b3 : a3;                        \
            _Pragma("unroll")                                                          \
            for (int c = 0; c < 8; ++c) {                                              \
                short8 vf = *(const short8*)&v_lds[(c * 16 + lr) * VPAD + kh * 32 + lg * 8]; \
                oacc[c] = __builtin_amdgcn_mfma_f32_16x16x32_bf16(vf, pf_.s8, oacc[c], 0, 0, 0); \
            }                                                                          \
        }                                                                              \
    }                                                                                  \
} while (0)

__global__ __launch_bounds__(512, 2)
void k_attn(const unsigned short* __restrict__ qkv,
            const unsigned short* __restrict__ vt,
            unsigned short* __restrict__ o)
{
    __shared__ unsigned short k_lds[64 * KPAD];
    __shared__ unsigned short v_lds[128 * VPAD];

    const int h = blockIdx.y, b = blockIdx.z;
    const int tid = threadIdx.x;
    const int lane = tid & 63, wave = tid >> 6;
    const int lg = lane >> 4, lr = lane & 15;
    const int hk = h >> 2;
    const int qlo = blockIdx.x, qhi = 15 - qlo;
    const int ntA = 2 * qlo + 2, ntB = 2 * qhi + 2;   // ntA + ntB == 34
    const int qbaseA = qlo * 128 + wave * 16;
    const int qbaseB = qhi * 128 + wave * 16;
    const int myA = ((qbaseA + 15) >> 6) + 1;
    const int myB = ((qbaseB + 15) >> 6) + 1;

    // Q fragments for both phases (B-operand; same layout as before)
    short8 qfA[4], qfB[4];
    {
        const unsigned short* qrA = qkv + (size_t)(b * S_ + qbaseA + lr) * NQKV_ + h * D_;
        const unsigned short* qrB = qkv + (size_t)(b * S_ + qbaseB + lr) * NQKV_ + h * D_;
        #pragma unroll
        for (int dc = 0; dc < 4; ++dc) {
            qfA[dc] = *(const short8*)(qrA + dc * 32 + lg * 8);
            qfB[dc] = *(const short8*)(qrB + dc * 32 + lg * 8);
        }
    }

    float m_run = -1e30f, l_run = 0.f;
    f32x4 oacc[8] = {};

    const unsigned short* kglob = qkv + (size_t)(b * S_) * NQKV_ + DIM_ + hk * D_;
    const unsigned short* vglob = vt + (size_t)(b * HKV_ + hk) * D_ * S_;

    // lane holds O[q = qb2+lr][d = c*16 + lg*4 + j] -> packed 8B stores
    auto writeO = [&](int qb2) {
        float inv = 1.0f / l_run;
        unsigned short* orow = o + (size_t)(b * S_ + qb2 + lr) * DIM_ + h * D_ + lg * 4;
        #pragma unroll
        for (int c = 0; c < 8; ++c) {
            union { unsigned short us[4]; unsigned long long u; } ov;
            #pragma unroll
            for (int j = 0; j < 4; ++j) ov.us[j] = f2bf(oacc[c][j] * inv);
            *(unsigned long long*)(orow + c * 16) = ov.u;
        }
    };

    short8 ks0, ks1, vs0, vs1;
    STAGE_LOAD(0);                                    // prologue: tile 0 of phase A

    // ---- phase A: q-tile qlo ----
    for (int t = 0; t < ntA; ++t) {
        int k0 = t * 64;
        int k0n = (t + 1 < ntA) ? (t + 1) * 64 : 0;   // phase B restarts at 0
        ATTN_TILE(qfA, qbaseA, myA, t, k0, 1, k0n);
    }
    writeO(qbaseA);
    m_run = -1e30f; l_run = 0.f;
    #pragma unroll
    for (int c = 0; c < 8; ++c) oacc[c] = (f32x4){0.f, 0.f, 0.f, 0.f};

    // ---- phase B: q-tile qhi ----
    for (int t = 0; t < ntB; ++t) {
        int k0 = t * 64;
        int k0n = (t + 1) * 64;
        ATTN_TILE(qfB, qbaseB, myB, t, k0, (t + 1 < ntB), k0n);
    }
    writeO(qbaseB);
}

// ----------------------------------------------------------------------
extern "C" void kernel_launch(void* const* d_in, const int* in_sizes, int n_in,
                              void* d_out, int out_size, void* d_ws, size_t ws_size,
                              hipStream_t stream)
{
    const float* x  = (const float*)d_in[0];
    const float* Wq = (const float*)d_in[1];
    const float* Wk = (const float*)d_in[2];
    const float* Wv = (const float*)d_in[3];
    const float* Wo = (const float*)d_in[4];
    float* out = (float*)d_out;

    char* ws = (char*)d_ws;
    unsigned short* xb    = (unsigned short*)(ws);
    unsigned short* wqkvt = (unsigned short*)(ws + 16777216);
    unsigned short* wot   = (unsigned short*)(ws + 29360128);
    unsigned short* qkv   = (unsigned short*)(ws + 37748736);
    unsigned short* vt    = (unsigned short*)(ws + 62914560);
    unsigned short* attno = (unsigned short*)(ws + 67108864);

    // 1. x -> bf16
    k_convert<<<(BS_ * DIM_ / 4) / 256, 256, 0, stream>>>(x, xb, BS_ * DIM_ / 4);

    // 2. weight transposes into bf16 B^T panels
    k_transpose<<<dim3(DIM_ / 64, DIM_ / 64), 256, 0, stream>>>(Wq, wqkvt, DIM_, 2048);
    k_transpose<<<dim3(DIM_ / 64, 512 / 64), 256, 0, stream>>>(Wk, wqkvt + (size_t)2048 * 2048, DIM_, 512);
    k_transpose<<<dim3(DIM_ / 64, 512 / 64), 256, 0, stream>>>(Wv, wqkvt + (size_t)2560 * 2048, DIM_, 512);
    k_transpose<<<dim3(DIM_ / 64, DIM_ / 64), 256, 0, stream>>>(Wo, wot, 2048, 2048);

    // 3. QKV projection GEMM
    k_gemm_bt<unsigned short><<<(BS_ / 128) * (NQKV_ / 128), 256, 0, stream>>>(
        xb, wqkvt, qkv, BS_, NQKV_, DIM_);

    // 4. RoPE in-place on Q and K
    k_rope<<<dim3(5, BS_), 256, 0, stream>>>(qkv);

    // 5. V -> vt[(b,hk)][d][s]
    k_vtrans<<<dim3(S_ / 64, D_ / 64, B_ * HKV_), 256, 0, stream>>>(qkv, vt);

    // 6. flash attention (paired q-tiles, swapped QK^T, in-register softmax)
    k_attn<<<dim3(8, H_, B_), 512, 0, stream>>>(qkv, vt, attno);

    // 7. output GEMM
    k_gemm_bt<float><<<(BS_ / 128) * (DIM_ / 128), 256, 0, stream>>>(
        attno, wot, out, BS_, DIM_, DIM_);
}